// Round 10
// baseline (358.666 us; speedup 1.0000x reference)
//
#include <hip/hip_runtime.h>

#define PH  72
#define HSZ 1152
#define XRW 144          // x frag-tile row stride (halves)
#define XSL 584          // per-t-slot stride (4*XRW + 8 pad) halves

typedef float f32x4 __attribute__((ext_vector_type(4)));
typedef _Float16 f16x8 __attribute__((ext_vector_type(8)));

__device__ __forceinline__ float sigmoid_f(float x) {
    float e = __builtin_amdgcn_exp2f(-1.4426950408889634f * x);
    return __builtin_amdgcn_rcpf(1.0f + e);
}
__device__ __forceinline__ float tanh_f(float x) {
    float e = __builtin_amdgcn_exp2f(-2.8853900817779268f * x);
    return 2.0f * __builtin_amdgcn_rcpf(1.0f + e) - 1.0f;
}
__device__ __forceinline__ f16x8 load_frag16h(const float* wp, int n, int K, int k0) {
    const float* wf = wp + (size_t)n * K + k0;
    f16x8 h;
    #pragma unroll
    for (int j = 0; j < 8; ++j) h[j] = (_Float16)wf[j];
    return h;
}
__device__ __forceinline__ void gload16(const void* g, void* l) {
    __builtin_amdgcn_global_load_lds(
        (const __attribute__((address_space(1))) unsigned int*)g,
        (__attribute__((address_space(3))) unsigned int*)l, 16, 0, 0);
}

#define MFMA16(a, b, c) __builtin_amdgcn_mfma_f32_16x16x32_f16(a, b, c, 0, 0, 0)

// ======= fused rec v12: v11 + 4-timestep-packed proj (pressure-minimized) =======
// 256 blocks x 768 thr (12 waves: 4 L1, 4 L0, 4 proj).
// v11 post-mortem: MFMA demand -29% but step only -4%; MfmaUtil 32% -> matrix
// pipe no longer binding. v9/v10 "phantom scratch" theory: launch_bounds(768,3)
// caps the UNIFIED VGPR+AGPR file at ~170/wave; v10's extraction held 16 acc
// regs + 4 o-vectors live -> hidden spill (VGPR_Count excludes AGPR).
// v12 retries v10's M-row timestep packing with minimal peak pressure:
//   proj batch every 4th step: A-row 4q+r = (staged row q, timestep tb+r);
//   output reg r = timestep tb+r (C/D row = quad*4 + reg).
//   Extraction: per-(g,r) SCALAR ds_write_b32, freeing each pa[g] immediately
//   (peak live ~24 regs vs v10's ~36).
// proj MFMA: 16/step -> 16 per 4 steps; per-SIMD 40 -> 28 avg.
// Schedule: batch@t%4==0 (tb=t+4, t<=248); issue@t%16==1 (chunk t/16+1, t<240);
// convert@t%16 in {4..7} (2 ibs each, t<240). Ring 8 slots (32 KB).
// Hazards: batch write(t) -> read(t+3) 3 barriers; overwrite at t+8: 5 barriers;
// convert chunk c+1 done 16c+7 < first batch use 16c+12. WRITE_SIZE tripwire.
__global__ __launch_bounds__(768, 3) void rec_fused(
    const float* __restrict__ x,
    const float* __restrict__ wih0, const float* __restrict__ whh0,
    const float* __restrict__ bih0, const float* __restrict__ bhh0,
    const float* __restrict__ wih1, const float* __restrict__ whh1,
    const float* __restrict__ bih1, const float* __restrict__ bhh1,
    const float* __restrict__ wfc,  const float* __restrict__ bfc,
    float* __restrict__ out)
{
    __shared__ float    xs32[4 * 2048];          // 32 KB staging strip
    __shared__ _Float16 xh[32 * XSL];            // 37,376 B x frags (f16)
    __shared__ float    xpl[8 * 1024];           // 32 KB xp ring (8 t-slots)
    __shared__ _Float16 h0[2 * HSZ], h1[2 * HSZ];
    const int tid = threadIdx.x, lane = tid & 63, w = tid >> 6;
    const int l16 = lane & 15, quad = lane >> 4, k0 = quad * 8;
    const int wl = w & 3;
    const int role = w >> 2;                     // 0=L1, 1=L0, 2=proj
    const bool is1 = (role == 0), is0 = (role == 1), isP = (role == 2);
    const int bb  = blockIdx.x & 63;
    const int sub = blockIdx.x >> 6;

    const float* xrow = x + (size_t)(bb * 16 + wl * 4 + sub) * 128 * 256;

    f16x8 fA[4][2], fB[4][4];
    float gb[4] = {0.f, 0.f, 0.f, 0.f};
    #pragma unroll
    for (int g = 0; g < 4; ++g) {
        const int n = g * 64 + wl * 16 + l16;
        if (is1) {
            #pragma unroll
            for (int ks = 0; ks < 2; ++ks) {
                fA[g][ks] = load_frag16h(wih1, n, 64, ks * 32 + k0);
                fB[g][ks] = load_frag16h(whh1, n, 64, ks * 32 + k0);
            }
            gb[g] = bih1[n] + bhh1[n];
        } else if (is0) {
            #pragma unroll
            for (int ks = 0; ks < 2; ++ks)
                fA[g][ks] = load_frag16h(whh0, n, 64, ks * 32 + k0);
        } else {
            #pragma unroll
            for (int ks = 0; ks < 4; ++ks)
                fB[g][ks] = load_frag16h(wih0, n, 128, ks * 32 + k0);
            gb[g] = bih0[n] + bhh0[n];
        }
    }
    for (int i = tid; i < 2 * HSZ; i += 768) { h0[i] = (_Float16)0.f; h1[i] = (_Float16)0.f; }
    float c = 0.f;       // lane's cell state (c1 for L1, c0 for L0)

    // ---- proj-wave helpers ----
    auto convert_rows = [&](int cc, int ib0, int nib) {
        const int sb = (cc & 1) * 16;
        const int tq = lane & 3;
        for (int ib = ib0; ib < ib0 + nib; ++ib) {
            const float4 v = *(const float4*)&xs32[wl * 2048 + ib * 256 + lane * 4];
            const int d = ib * 16 + (lane >> 2);
            const float vv[4] = {v.x, v.y, v.z, v.w};
            #pragma unroll
            for (int j = 0; j < 4; ++j)
                xh[(sb + tq * 4 + j) * XSL + wl * XRW + d] = (_Float16)vv[j];
        }
    };
    auto issue_chunk = [&](int cc) {
        #pragma unroll
        for (int ib = 0; ib < 8; ++ib)
            gload16(xrow + (size_t)(ib * 16 + (lane >> 2)) * 256 + cc * 16 + (lane & 3) * 4,
                    (char*)xs32 + wl * 8192 + ib * 1024);
    };
    // 4-timestep-packed xp batch: produces xp[tb..tb+3] (tb % 4 == 0).
    // Per-lane A-row m = l16: staged row l16>>2, timestep tb + (l16&3).
    // Extraction: per-(g,r) scalar writes; pa[g] freed right after its 4 stores.
    auto compute_xp4 = [&](int tb) {
        const int tpl = tb + (l16 & 3);
        const int fs  = ((tpl >> 4) & 1) * 16 + (tpl & 15);
        f16x8 ax[4];
        #pragma unroll
        for (int ks = 0; ks < 4; ++ks)
            ax[ks] = *(const f16x8*)&xh[fs * XSL + (l16 >> 2) * XRW + ks * 32 + k0];
        #pragma unroll
        for (int g = 0; g < 4; ++g) {
            f32x4 pa = (f32x4){gb[g], gb[g], gb[g], gb[g]};
            #pragma unroll
            for (int ks = 0; ks < 4; ++ks)
                pa = MFMA16(ax[ks], fB[g][ks], pa);
            #pragma unroll
            for (int r = 0; r < 4; ++r)
                xpl[((((tb + r) & 7) * 4 + wl) * 64 + lane) * 4 + g] = pa[r];
        }
    };
    // hi/lo h store: row quad*4 = hi, row quad*4+1 = residual
    auto store_h = [&](_Float16* hbuf, int slot, float hv) {
        const _Float16 hh = (_Float16)hv;
        const int base = slot * HSZ + (quad * 4) * PH + wl * 16 + l16;
        hbuf[base]      = hh;
        hbuf[base + PH] = (_Float16)(hv - (float)hh);
    };

    if (isP) issue_chunk(0);
    __syncthreads();                 // chunk0 drained; h zeroed
    if (isP) convert_rows(0, 0, 8);  // chunk0 -> frags (chunk1 issued in-loop t=1)
    __syncthreads();                 // xh chunk0 visible
    if (isP) compute_xp4(0);         // xp[0..3]
    __syncthreads();                 // xp[0..3] visible
    if (is0) {                       // prologue: layer0 t=0 (h=0)
        const f32x4 xp4 = *(const f32x4*)&xpl[(wl * 64 + lane) * 4];
        const float gi = sigmoid_f(xp4[0]);
        const float gg = tanh_f(xp4[2]);
        const float go = sigmoid_f(xp4[3]);
        c = gi * gg;
        store_h(h0, 0, go * tanh_f(c));
    }
    __syncthreads();

    for (int t = 0; t < 255; ++t) {
        const int s0 = t & 1, s1 = s0 ^ 1;
        const int tn = t + 1;
        if (is1) {
            f16x8 ah[2], bh[2];
            #pragma unroll
            for (int ks = 0; ks < 2; ++ks) {
                ah[ks] = *(const f16x8*)&h0[s0 * HSZ + l16 * PH + ks * 32 + k0];
                bh[ks] = *(const f16x8*)&h1[s1 * HSZ + l16 * PH + ks * 32 + k0];
            }
            f32x4 acc[4];
            #pragma unroll
            for (int g = 0; g < 4; ++g)
                acc[g] = (f32x4){gb[g], 0.f, 0.f, 0.f};
            #pragma unroll
            for (int g = 0; g < 4; ++g)
                #pragma unroll
                for (int ks = 0; ks < 2; ++ks) {
                    acc[g] = MFMA16(ah[ks], fA[g][ks], acc[g]);
                    acc[g] = MFMA16(bh[ks], fB[g][ks], acc[g]);
                }
            const float gi = sigmoid_f(acc[0][0] + acc[0][1]);
            const float gf = sigmoid_f(acc[1][0] + acc[1][1]);
            const float gg = tanh_f(acc[2][0] + acc[2][1]);
            const float go = sigmoid_f(acc[3][0] + acc[3][1]);
            c = gf * c + gi * gg;
            store_h(h1, s0, go * tanh_f(c));
        } else if (is0) {
            const f32x4 xp4 =
                *(const f32x4*)&xpl[(((tn & 7) * 4 + wl) * 64 + lane) * 4];
            f16x8 ah[2];
            #pragma unroll
            for (int ks = 0; ks < 2; ++ks)
                ah[ks] = *(const f16x8*)&h0[s0 * HSZ + l16 * PH + ks * 32 + k0];
            f32x4 acc[4];
            #pragma unroll
            for (int g = 0; g < 4; ++g)
                acc[g] = (f32x4){xp4[g], 0.f, 0.f, 0.f};
            #pragma unroll
            for (int g = 0; g < 4; ++g)
                #pragma unroll
                for (int ks = 0; ks < 2; ++ks)
                    acc[g] = MFMA16(ah[ks], fA[g][ks], acc[g]);
            const float gi = sigmoid_f(acc[0][0] + acc[0][1]);
            const float gf = sigmoid_f(acc[1][0] + acc[1][1]);
            const float gg = tanh_f(acc[2][0] + acc[2][1]);
            const float go = sigmoid_f(acc[3][0] + acc[3][1]);
            c = gf * c + gi * gg;
            store_h(h0, s1, go * tanh_f(c));
        } else {
            if ((t & 3) == 0 && t <= 248)           // 4-t xp batch (tb=t+4)
                compute_xp4(t + 4);
            if ((t & 15) == 1 && t < 240)           // issue chunk t/16+1 (DMA)
                issue_chunk((t >> 4) + 1);
            const int m16 = t & 15;
            if (m16 >= 4 && m16 < 8 && t < 240)     // convert chunk t/16+1
                convert_rows((t >> 4) + 1, (m16 - 4) * 2, 2);
        }
        __syncthreads();
    }

    if (is1) {   // epilogue: layer1[255] (h0 slot1, h1 slot0 -> h1 slot1)
        f16x8 ah[2], bh[2];
        #pragma unroll
        for (int ks = 0; ks < 2; ++ks) {
            ah[ks] = *(const f16x8*)&h0[HSZ + l16 * PH + ks * 32 + k0];
            bh[ks] = *(const f16x8*)&h1[l16 * PH + ks * 32 + k0];
        }
        f32x4 acc[4];
        #pragma unroll
        for (int g = 0; g < 4; ++g)
            acc[g] = (f32x4){gb[g], 0.f, 0.f, 0.f};
        #pragma unroll
        for (int g = 0; g < 4; ++g)
            #pragma unroll
            for (int ks = 0; ks < 2; ++ks) {
                acc[g] = MFMA16(ah[ks], fA[g][ks], acc[g]);
                acc[g] = MFMA16(bh[ks], fB[g][ks], acc[g]);
            }
        const float gi = sigmoid_f(acc[0][0] + acc[0][1]);
        const float gf = sigmoid_f(acc[1][0] + acc[1][1]);
        const float gg = tanh_f(acc[2][0] + acc[2][1]);
        const float go = sigmoid_f(acc[3][0] + acc[3][1]);
        c = gf * c + gi * gg;
        store_h(h1, 1, go * tanh_f(c));
    }
    __syncthreads();

    // head: rows sel*4 (hi) + sel*4+1 (lo) of slot 1; out row = bb*16+sel*4+sub
    if (tid < 512) {
        const int n   = tid & 127;
        const int sel = tid >> 7;
        float s = 0.f;
        for (int k = 0; k < 64; ++k)
            s += ((float)h1[HSZ + (sel * 4) * PH + k]
                + (float)h1[HSZ + (sel * 4 + 1) * PH + k]) * wfc[n * 64 + k];
        out[(size_t)(bb * 16 + sel * 4 + sub) * 128 + n] = s + bfc[n];
    }
}

extern "C" void kernel_launch(void* const* d_in, const int* in_sizes, int n_in,
                              void* d_out, int out_size, void* d_ws, size_t ws_size,
                              hipStream_t stream) {
    const float* x     = (const float*)d_in[0];
    const float* wih0  = (const float*)d_in[1];
    const float* whh0  = (const float*)d_in[2];
    const float* bih0  = (const float*)d_in[3];
    const float* bhh0  = (const float*)d_in[4];
    const float* wih1  = (const float*)d_in[5];
    const float* whh1  = (const float*)d_in[6];
    const float* bih1  = (const float*)d_in[7];
    const float* bhh1  = (const float*)d_in[8];
    const float* wfc   = (const float*)d_in[9];
    const float* bfc   = (const float*)d_in[10];
    float* out = (float*)d_out;

    rec_fused<<<256, 768, 0, stream>>>(x, wih0, whh0, bih0, bhh0,
                                       wih1, whh1, bih1, bhh1, wfc, bfc, out);
}